// Round 6
// baseline (432.320 us; speedup 1.0000x reference)
//
#include <hip/hip_runtime.h>
#include <hip/hip_bf16.h>

typedef __attribute__((ext_vector_type(8))) short s16x8;
typedef __attribute__((ext_vector_type(4))) float f32x4;

__device__ __forceinline__ unsigned short f2bf(float x) {
    unsigned int u = __float_as_uint(x);
    u += 0x7fffu + ((u >> 16) & 1u);          // round-to-nearest-even
    return (unsigned short)(u >> 16);
}
__device__ __forceinline__ float bf2f(unsigned short h) {
    return __uint_as_float((unsigned int)h << 16);
}
__device__ __forceinline__ s16x8 pack8(float4 a, float4 b) {
    return (s16x8){ (short)f2bf(a.x), (short)f2bf(a.y), (short)f2bf(a.z), (short)f2bf(a.w),
                    (short)f2bf(b.x), (short)f2bf(b.y), (short)f2bf(b.z), (short)f2bf(b.w) };
}
__device__ __forceinline__ void gload_lds16(const void* g, void* l) {
    __builtin_amdgcn_global_load_lds(
        (const __attribute__((address_space(1))) void*)g,
        (__attribute__((address_space(3))) void*)(unsigned int)(size_t)l,
        16, 0, 0);
}
__device__ __forceinline__ float sigf(float x) { return 1.f / (1.f + __expf(-x)); }
__device__ __forceinline__ float tanhfast(float x) {
    return 1.f - 2.f / (__expf(2.f * x) + 1.f);
}

// ---- prep_w: fold W_cat into W_ih; bf16 weights; zero inv; tag inv ----
// inv zero/tag races are benign: copy runs BEFORE gru, and gru overwrites all
// updated rows (mem + lu), so a lost tag only costs one redundant row copy.
__global__ void prep_w_kernel(const float* __restrict__ W_cat,
                              const float* __restrict__ b_cat,
                              const float* __restrict__ W_ih,
                              const float* __restrict__ W_hh,
                              const float* __restrict__ b_ih,
                              const int* __restrict__ ids,
                              unsigned short* __restrict__ wm,
                              unsigned short* __restrict__ whh,
                              float* __restrict__ wamt,
                              float* __restrict__ bcomb,
                              int* __restrict__ inv,
                              int N, int M) {
    int idx = blockIdx.x * blockDim.x + threadIdx.x;
    const int NW = 768 * 256;
    if (idx < NW) {
        int g = idx >> 8, c = idx & 255;
        float s = 0.f;
        #pragma unroll 4
        for (int k = 0; k < 256; ++k) s += W_ih[g * 256 + k] * W_cat[k * 257 + c];
        wm[idx] = f2bf(s);
    } else if (idx < 2 * NW) {
        int t = idx - NW;
        whh[t] = f2bf(W_hh[t]);
    } else if (idx < 2 * NW + 768) {
        int g = idx - 2 * NW;
        float sa = 0.f, sb = 0.f;
        for (int k = 0; k < 256; ++k) {
            float w = W_ih[g * 256 + k];
            sa += w * W_cat[k * 257 + 256];
            sb += w * b_cat[k];
        }
        wamt[g] = sa;
        bcomb[g] = sb + b_ih[g];
    } else if (idx < 2 * NW + 768 + N) {
        inv[idx - (2 * NW + 768)] = 0;
    } else if (idx < 2 * NW + 768 + N + M) {
        int i = idx - (2 * NW + 768 + N);
        inv[ids[i]] = i + 1;
    }
}

// ---------------- copy: non-updated rows; lu bulk (gru overwrites) ----------------
__global__ __launch_bounds__(256)
void copy_kernel(const float* __restrict__ memory,
                 const int* __restrict__ inv,
                 const float* __restrict__ lu,
                 float* __restrict__ out_mem,
                 float* __restrict__ out_lu,
                 int N) {
    int wid = (blockIdx.x * blockDim.x + threadIdx.x) >> 6;
    int lane = threadIdx.x & 63;
    int nw = (gridDim.x * blockDim.x) >> 6;
    for (int base = wid; base < N; base += nw * 4) {
        int  r0 = base, r1 = base + nw, r2 = base + 2 * nw, r3 = base + 3 * nw;
        bool d0 = (r0 < N) && (inv[r0] == 0);
        bool d1 = (r1 < N) && (inv[r1] == 0);
        bool d2 = (r2 < N) && (inv[r2] == 0);
        bool d3 = (r3 < N) && (inv[r3] == 0);
        float4 v0, v1, v2, v3;
        if (d0) v0 = ((const float4*)(memory + (size_t)r0 * 256))[lane];
        if (d1) v1 = ((const float4*)(memory + (size_t)r1 * 256))[lane];
        if (d2) v2 = ((const float4*)(memory + (size_t)r2 * 256))[lane];
        if (d3) v3 = ((const float4*)(memory + (size_t)r3 * 256))[lane];
        if (d0) ((float4*)(out_mem + (size_t)r0 * 256))[lane] = v0;
        if (d1) ((float4*)(out_mem + (size_t)r1 * 256))[lane] = v1;
        if (d2) ((float4*)(out_mem + (size_t)r2 * 256))[lane] = v2;
        if (d3) ((float4*)(out_mem + (size_t)r3 * 256))[lane] = v3;
    }
    // last_update bulk: gru (runs after) overwrites updated entries
    int gidx = blockIdx.x * blockDim.x + threadIdx.x;
    int stride = gridDim.x * blockDim.x;
    for (int i = gidx; i < N; i += stride) out_lu[i] = lu[i];
}

// ---------------- fused GRU (R4 structure): 128x64 tile, 512 thr ----------------
// A (msgs, gathered h) staged from f32 via reg round-trip (T14 split: loads
// issued before MFMA phase, pack+ds_write after barrier). Weights DMA'd bf16,
// DOUBLE-buffered, next-chunk DMA issued before compute. K-chunks rotated so
// chunk nc is last -> sh holds h[:, nc*64..) at epilogue (hv from LDS).
__device__ __forceinline__ void dma_w(const unsigned short* __restrict__ wm,
                                      const unsigned short* __restrict__ whh,
                                      int nc, int k0, char* swbuf, int tid) {
    #pragma unroll
    for (int it = 0; it < 6; ++it) {
        int q = tid + it * 512;
        int r = q >> 3;
        int part = (q & 7) ^ (r & 7);
        int pn = r >> 6, rr = r & 63;
        const unsigned short* src = (pn < 3)
            ? wm  + ((size_t)(pn * 256 + nc * 64 + rr)) * 256
            : whh + ((size_t)((pn - 3) * 256 + nc * 64 + rr)) * 256;
        gload_lds16((const char*)src + k0 * 2 + part * 16,
                    swbuf + (tid & ~63) * 16 + it * 8192);
    }
}

__global__ __launch_bounds__(512, 2)
void gru_kernel(const int* __restrict__ ids,
                const float* __restrict__ msgs,
                const float* __restrict__ memory,
                const unsigned short* __restrict__ wm,
                const unsigned short* __restrict__ whh,
                const float* __restrict__ wamt,
                const float* __restrict__ bcomb,
                const float* __restrict__ b_hh,
                const float* __restrict__ amt,
                const float* __restrict__ ts,
                float* __restrict__ out_mem,
                float* __restrict__ out_lu,
                int M, int mtiles) {
    extern __shared__ char lds[];
    char* sm  = lds;                 // 16384: msgs slice [128][64 bf16] swizzled
    char* sh  = lds + 16384;         // 16384: h slice
    char* sw0 = lds + 32768;         // 49152: W panels buf 0
    char* sw1 = lds + 81920;         // 49152: W panels buf 1   (total 131072)

    int g = blockIdx.x;
    int xcd = g & 7, s = g >> 3;
    int nc = s & 3;
    int mtile = (s >> 2) * 8 + xcd;  // 4 nc-blocks of one mtile share an XCD L2
    if (mtile >= mtiles) return;
    int m0 = mtile * 128;

    int tid = threadIdx.x;
    int lane = tid & 63;
    int w = tid >> 6;
    int wr = w >> 2, wc = w & 3;     // wave = 64 rows x 16 cols

    // fixed staging coordinates (rows don't change across chunks)
    int row0 = tid >> 3, row1 = (tid + 512) >> 3;
    int part = tid & 7;              // (tid+512)&7 == tid&7
    int gr0 = m0 + row0; if (gr0 >= M) gr0 = M - 1;
    int gr1 = m0 + row1; if (gr1 >= M) gr1 = M - 1;
    const float* mp0 = msgs + (size_t)gr0 * 256 + part * 8;
    const float* mp1 = msgs + (size_t)gr1 * 256 + part * 8;
    const float* hp0 = memory + (size_t)ids[gr0] * 256 + part * 8;
    const float* hp1 = memory + (size_t)ids[gr1] * 256 + part * 8;
    int ld0 = row0 * 128 + ((part ^ (row0 & 7)) * 16);
    int ld1 = row1 * 128 + ((part ^ (row1 & 7)) * 16);

    float4 ma0, mb0, ma1, mb1, ha0, hb0, ha1, hb1;
    // ---- prologue: first chunk in rotated order ----
    {
        int k0 = ((nc + 1) & 3) * 64;
        ma0 = *(const float4*)(mp0 + k0);  mb0 = *(const float4*)(mp0 + k0 + 4);
        ma1 = *(const float4*)(mp1 + k0);  mb1 = *(const float4*)(mp1 + k0 + 4);
        ha0 = *(const float4*)(hp0 + k0);  hb0 = *(const float4*)(hp0 + k0 + 4);
        ha1 = *(const float4*)(hp1 + k0);  hb1 = *(const float4*)(hp1 + k0 + 4);
        dma_w(wm, whh, nc, k0, sw0, tid);
        *(s16x8*)(sm + ld0) = pack8(ma0, mb0);
        *(s16x8*)(sm + ld1) = pack8(ma1, mb1);
        *(s16x8*)(sh + ld0) = pack8(ha0, hb0);
        *(s16x8*)(sh + ld1) = pack8(ha1, hb1);
    }
    __syncthreads();                 // drains DMA chunk + ds_writes

    f32x4 acc[6][4];
    #pragma unroll
    for (int pn = 0; pn < 6; ++pn)
        #pragma unroll
        for (int mf = 0; mf < 4; ++mf) acc[pn][mf] = (f32x4){0.f, 0.f, 0.f, 0.f};

    #pragma unroll
    for (int ks = 0; ks < 4; ++ks) {
        char* swc = (ks & 1) ? sw1 : sw0;
        if (ks < 3) {                // issue next-chunk loads (latency hides under MFMA)
            int k0 = ((nc + 2 + ks) & 3) * 64;       // rotated order, last = nc
            ma0 = *(const float4*)(mp0 + k0);  mb0 = *(const float4*)(mp0 + k0 + 4);
            ma1 = *(const float4*)(mp1 + k0);  mb1 = *(const float4*)(mp1 + k0 + 4);
            ha0 = *(const float4*)(hp0 + k0);  hb0 = *(const float4*)(hp0 + k0 + 4);
            ha1 = *(const float4*)(hp1 + k0);  hb1 = *(const float4*)(hp1 + k0 + 4);
            dma_w(wm, whh, nc, k0, (ks & 1) ? sw0 : sw1, tid);
        }
        #pragma unroll
        for (int c = 0; c < 2; ++c) {
            int p = c * 4 + (lane >> 4);
            s16x8 ax[4], ah[4], bw[6];
            #pragma unroll
            for (int mf = 0; mf < 4; ++mf) {
                int row = wr * 64 + mf * 16 + (lane & 15);
                int off = row * 128 + ((p ^ (row & 7)) * 16);
                ax[mf] = *(const s16x8*)(sm + off);
                ah[mf] = *(const s16x8*)(sh + off);
            }
            #pragma unroll
            for (int pn = 0; pn < 6; ++pn) {
                int r = pn * 64 + wc * 16 + (lane & 15);
                bw[pn] = *(const s16x8*)(swc + r * 128 + ((p ^ (r & 7)) * 16));
            }
            #pragma unroll
            for (int pn = 0; pn < 6; ++pn)
                #pragma unroll
                for (int mf = 0; mf < 4; ++mf)
                    acc[pn][mf] = __builtin_amdgcn_mfma_f32_16x16x32_bf16(
                        (pn < 3) ? ax[mf] : ah[mf], bw[pn], acc[pn][mf], 0, 0, 0);
        }
        if (ks < 3) {
            __syncthreads();         // all waves done reading sm/sh; vmcnt drained
            *(s16x8*)(sm + ld0) = pack8(ma0, mb0);
            *(s16x8*)(sm + ld1) = pack8(ma1, mb1);
            *(s16x8*)(sh + ld0) = pack8(ha0, hb0);
            *(s16x8*)(sh + ld1) = pack8(ha1, hb1);
            __syncthreads();
        }
    }

    // ---- epilogue: gates + blend + scatter; hv from sh (holds chunk nc) ----
    int colL = wc * 16 + (lane & 15);
    int col = nc * 64 + colL;
    float bi0 = bcomb[col], bi1 = bcomb[256 + col], bi2 = bcomb[512 + col];
    float bh0 = b_hh[col],  bh1 = b_hh[256 + col],  bh2 = b_hh[512 + col];
    float wa0 = wamt[col],  wa1 = wamt[256 + col],  wa2 = wamt[512 + col];
    int hpart = colL >> 3, hbyte = (colL & 7) << 1;
    bool lu_thread = (nc == 0) && (colL == 0);
    #pragma unroll
    for (int mf = 0; mf < 4; ++mf) {
        int rb = wr * 64 + mf * 16 + (lane >> 4) * 4;
        #pragma unroll
        for (int r = 0; r < 4; ++r) {
            int rl = rb + r;
            int grow = m0 + rl; if (grow >= M) grow = M - 1;
            int gid = ids[grow];
            float amtv = amt[grow];
            float hv = bf2f(*(const unsigned short*)(
                sh + rl * 128 + ((hpart ^ (rl & 7)) << 4) + hbyte));
            float ir = acc[0][mf][r] + bi0 + amtv * wa0;
            float iz = acc[1][mf][r] + bi1 + amtv * wa1;
            float in_ = acc[2][mf][r] + bi2 + amtv * wa2;
            float hr = acc[3][mf][r] + bh0;
            float hz = acc[4][mf][r] + bh1;
            float hn = acc[5][mf][r] + bh2;
            float rg = sigf(ir + hr);
            float zg = sigf(iz + hz);
            float ng = tanhfast(in_ + rg * hn);
            out_mem[(size_t)gid * 256 + col] = (1.f - zg) * ng + zg * hv;
            if (lu_thread) out_lu[gid] = ts[grow];
        }
    }
}

extern "C" void kernel_launch(void* const* d_in, const int* in_sizes, int n_in,
                              void* d_out, int out_size, void* d_ws, size_t ws_size,
                              hipStream_t stream) {
    const int*   ids   = (const int*)  d_in[0];
    const float* msgs  = (const float*)d_in[1];
    const float* ts    = (const float*)d_in[2];
    const float* amt   = (const float*)d_in[3];
    const float* mem   = (const float*)d_in[4];
    const float* lu    = (const float*)d_in[5];
    const float* W_cat = (const float*)d_in[6];
    const float* b_cat = (const float*)d_in[7];
    const float* W_ih  = (const float*)d_in[8];
    const float* W_hh  = (const float*)d_in[9];
    const float* b_ih  = (const float*)d_in[10];
    const float* b_hh  = (const float*)d_in[11];

    int M = in_sizes[0];
    int N = in_sizes[5];

    float* out_mem = (float*)d_out;
    float* out_lu  = out_mem + (size_t)N * 256;

    // ws layout: wm 384KB | whh 384KB | wamt 3KB | bcomb 3KB | inv 4N
    char* ws = (char*)d_ws;
    unsigned short* wm    = (unsigned short*)ws;
    unsigned short* whh   = wm + 768 * 256;
    float*          wamt  = (float*)(whh + 768 * 256);
    float*          bcomb = wamt + 768;
    int*            inv   = (int*)(bcomb + 768);

    int prep_items = 2 * 768 * 256 + 768 + N + M;
    prep_w_kernel<<<(prep_items + 255) / 256, 256, 0, stream>>>(
        W_cat, b_cat, W_ih, W_hh, b_ih, ids, wm, whh, wamt, bcomb, inv, N, M);

    copy_kernel<<<2048, 256, 0, stream>>>(mem, inv, lu, out_mem, out_lu, N);

    int mtiles = (M + 127) / 128;
    int mt8 = ((mtiles + 7) / 8) * 8;
    (void)hipFuncSetAttribute((const void*)gru_kernel,
                              hipFuncAttributeMaxDynamicSharedMemorySize, 131072);
    gru_kernel<<<mt8 * 4, 512, 131072, stream>>>(
        ids, msgs, mem, wm, whh, wamt, bcomb, b_hh, amt, ts,
        out_mem, out_lu, M, mtiles);
}

// Round 7
// 396.631 us; speedup vs baseline: 1.0900x; 1.0900x over previous
//
#include <hip/hip_runtime.h>
#include <hip/hip_bf16.h>

typedef __attribute__((ext_vector_type(8))) short s16x8;
typedef __attribute__((ext_vector_type(4))) float f32x4;

__device__ __forceinline__ unsigned short f2bf(float x) {
    unsigned int u = __float_as_uint(x);
    u += 0x7fffu + ((u >> 16) & 1u);          // round-to-nearest-even
    return (unsigned short)(u >> 16);
}
__device__ __forceinline__ float bf2f(unsigned short h) {
    return __uint_as_float((unsigned int)h << 16);
}
__device__ __forceinline__ s16x8 pack8(float4 a, float4 b) {
    return (s16x8){ (short)f2bf(a.x), (short)f2bf(a.y), (short)f2bf(a.z), (short)f2bf(a.w),
                    (short)f2bf(b.x), (short)f2bf(b.y), (short)f2bf(b.z), (short)f2bf(b.w) };
}
__device__ __forceinline__ void gload_lds16(const void* g, void* l) {
    __builtin_amdgcn_global_load_lds(
        (const __attribute__((address_space(1))) void*)g,
        (__attribute__((address_space(3))) void*)(unsigned int)(size_t)l,
        16, 0, 0);
}
__device__ __forceinline__ float sigf(float x) { return 1.f / (1.f + __expf(-x)); }
__device__ __forceinline__ float tanhfast(float x) {
    return 1.f - 2.f / (__expf(2.f * x) + 1.f);
}

// ---- prep_w: fold W_cat into W_ih; bf16 weights; + build inv (tail range) ----
__global__ void prep_w_kernel(const float* __restrict__ W_cat,
                              const float* __restrict__ b_cat,
                              const float* __restrict__ W_ih,
                              const float* __restrict__ W_hh,
                              const float* __restrict__ b_ih,
                              const int* __restrict__ ids,
                              unsigned short* __restrict__ wm,
                              unsigned short* __restrict__ whh,
                              float* __restrict__ wamt,
                              float* __restrict__ bcomb,
                              int* __restrict__ inv,
                              int M) {
    int idx = blockIdx.x * blockDim.x + threadIdx.x;
    const int NW = 768 * 256;
    if (idx < NW) {
        int g = idx >> 8, c = idx & 255;
        float s = 0.f;
        #pragma unroll 4
        for (int k = 0; k < 256; ++k) s += W_ih[g * 256 + k] * W_cat[k * 257 + c];
        wm[idx] = f2bf(s);
    } else if (idx < 2 * NW) {
        int t = idx - NW;
        whh[t] = f2bf(W_hh[t]);
    } else if (idx < 2 * NW + 768) {
        int g = idx - 2 * NW;
        float sa = 0.f, sb = 0.f;
        for (int k = 0; k < 256; ++k) {
            float w = W_ih[g * 256 + k];
            sa += w * W_cat[k * 257 + 256];
            sb += w * b_cat[k];
        }
        wamt[g] = sa;
        bcomb[g] = sb + b_ih[g];
    } else if (idx < 2 * NW + 768 + M) {
        int i = idx - (2 * NW + 768);
        inv[ids[i]] = i + 1;                   // inv pre-zeroed by memset
    }
}

// ---------------- fused GRU: gi/gh GEMM + gates + scatter ----------------
// Tile: 128 rows x 64 cols x 6 panels. A (msgs, gathered h) staged from f32
// via reg round-trip (T14 split). Weights DMA'd bf16, double-buffered.
// K-chunks processed in rotated order so chunk `nc` is LAST -> sh still holds
// h[:, nc*64..nc*64+64) at epilogue; hv comes from LDS, not global.
__device__ __forceinline__ void dma_w(const unsigned short* __restrict__ wm,
                                      const unsigned short* __restrict__ whh,
                                      int nc, int k0, char* swbuf, int tid) {
    #pragma unroll
    for (int it = 0; it < 6; ++it) {
        int q = tid + it * 512;
        int r = q >> 3;
        int part = (q & 7) ^ (r & 7);
        int pn = r >> 6, rr = r & 63;
        const unsigned short* src = (pn < 3)
            ? wm  + ((size_t)(pn * 256 + nc * 64 + rr)) * 256
            : whh + ((size_t)((pn - 3) * 256 + nc * 64 + rr)) * 256;
        gload_lds16((const char*)src + k0 * 2 + part * 16,
                    swbuf + (tid & ~63) * 16 + it * 8192);
    }
}

__global__ __launch_bounds__(512, 2)
void gru_kernel(const int* __restrict__ ids,
                const float* __restrict__ msgs,
                const float* __restrict__ memory,
                const unsigned short* __restrict__ wm,
                const unsigned short* __restrict__ whh,
                const float* __restrict__ wamt,
                const float* __restrict__ bcomb,
                const float* __restrict__ b_hh,
                const float* __restrict__ amt,
                float* __restrict__ out_mem,
                int M, int mtiles) {
    extern __shared__ char lds[];
    char* sm  = lds;                 // 16384: msgs slice [128][64 bf16] swizzled
    char* sh  = lds + 16384;         // 16384: h slice
    char* sw0 = lds + 32768;         // 49152: W panels buf 0
    char* sw1 = lds + 81920;         // 49152: W panels buf 1   (total 131072)

    int g = blockIdx.x;
    int xcd = g & 7, s = g >> 3;
    int nc = s & 3;
    int mtile = (s >> 2) * 8 + xcd;  // 4 nc-blocks of one mtile share an XCD L2
    if (mtile >= mtiles) return;
    int m0 = mtile * 128;

    int tid = threadIdx.x;
    int lane = tid & 63;
    int w = tid >> 6;
    int wr = w >> 2, wc = w & 3;     // wave = 64 rows x 16 cols

    // fixed staging coordinates (rows don't change across chunks)
    int row0 = tid >> 3, row1 = (tid + 512) >> 3;
    int part = tid & 7;              // (tid+512)&7 == tid&7
    int gr0 = m0 + row0; if (gr0 >= M) gr0 = M - 1;
    int gr1 = m0 + row1; if (gr1 >= M) gr1 = M - 1;
    const float* mp0 = msgs + (size_t)gr0 * 256 + part * 8;
    const float* mp1 = msgs + (size_t)gr1 * 256 + part * 8;
    const float* hp0 = memory + (size_t)ids[gr0] * 256 + part * 8;
    const float* hp1 = memory + (size_t)ids[gr1] * 256 + part * 8;
    int ld0 = row0 * 128 + ((part ^ (row0 & 7)) * 16);
    int ld1 = row1 * 128 + ((part ^ (row1 & 7)) * 16);

    float4 ma0, mb0, ma1, mb1, ha0, hb0, ha1, hb1;
    // ---- prologue: first chunk in rotated order ----
    {
        int k0 = ((nc + 1) & 3) * 64;
        ma0 = *(const float4*)(mp0 + k0);  mb0 = *(const float4*)(mp0 + k0 + 4);
        ma1 = *(const float4*)(mp1 + k0);  mb1 = *(const float4*)(mp1 + k0 + 4);
        ha0 = *(const float4*)(hp0 + k0);  hb0 = *(const float4*)(hp0 + k0 + 4);
        ha1 = *(const float4*)(hp1 + k0);  hb1 = *(const float4*)(hp1 + k0 + 4);
        dma_w(wm, whh, nc, k0, sw0, tid);
        *(s16x8*)(sm + ld0) = pack8(ma0, mb0);
        *(s16x8*)(sm + ld1) = pack8(ma1, mb1);
        *(s16x8*)(sh + ld0) = pack8(ha0, hb0);
        *(s16x8*)(sh + ld1) = pack8(ha1, hb1);
    }
    __syncthreads();                 // drains DMA chunk + ds_writes

    f32x4 acc[6][4];
    #pragma unroll
    for (int pn = 0; pn < 6; ++pn)
        #pragma unroll
        for (int mf = 0; mf < 4; ++mf) acc[pn][mf] = (f32x4){0.f, 0.f, 0.f, 0.f};

    #pragma unroll
    for (int ks = 0; ks < 4; ++ks) {
        char* swc = (ks & 1) ? sw1 : sw0;
        if (ks < 3) {                // issue next-chunk loads (latency hides under MFMA)
            int k0 = ((nc + 2 + ks) & 3) * 64;       // rotated order, last = nc
            ma0 = *(const float4*)(mp0 + k0);  mb0 = *(const float4*)(mp0 + k0 + 4);
            ma1 = *(const float4*)(mp1 + k0);  mb1 = *(const float4*)(mp1 + k0 + 4);
            ha0 = *(const float4*)(hp0 + k0);  hb0 = *(const float4*)(hp0 + k0 + 4);
            ha1 = *(const float4*)(hp1 + k0);  hb1 = *(const float4*)(hp1 + k0 + 4);
            dma_w(wm, whh, nc, k0, (ks & 1) ? sw0 : sw1, tid);
        }
        #pragma unroll
        for (int c = 0; c < 2; ++c) {
            int p = c * 4 + (lane >> 4);
            s16x8 ax[4], ah[4], bw[6];
            #pragma unroll
            for (int mf = 0; mf < 4; ++mf) {
                int row = wr * 64 + mf * 16 + (lane & 15);
                int off = row * 128 + ((p ^ (row & 7)) * 16);
                ax[mf] = *(const s16x8*)(sm + off);
                ah[mf] = *(const s16x8*)(sh + off);
            }
            #pragma unroll
            for (int pn = 0; pn < 6; ++pn) {
                int r = pn * 64 + wc * 16 + (lane & 15);
                bw[pn] = *(const s16x8*)(swc + r * 128 + ((p ^ (r & 7)) * 16));
            }
            #pragma unroll
            for (int pn = 0; pn < 6; ++pn)
                #pragma unroll
                for (int mf = 0; mf < 4; ++mf)
                    acc[pn][mf] = __builtin_amdgcn_mfma_f32_16x16x32_bf16(
                        (pn < 3) ? ax[mf] : ah[mf], bw[pn], acc[pn][mf], 0, 0, 0);
        }
        if (ks < 3) {
            __syncthreads();         // all waves done reading sm/sh; vmcnt drained
            *(s16x8*)(sm + ld0) = pack8(ma0, mb0);
            *(s16x8*)(sm + ld1) = pack8(ma1, mb1);
            *(s16x8*)(sh + ld0) = pack8(ha0, hb0);
            *(s16x8*)(sh + ld1) = pack8(ha1, hb1);
            __syncthreads();
        }
    }

    // ---- epilogue: gates + blend + scatter; hv from sh (holds chunk nc) ----
    int colL = wc * 16 + (lane & 15);
    int col = nc * 64 + colL;
    float bi0 = bcomb[col], bi1 = bcomb[256 + col], bi2 = bcomb[512 + col];
    float bh0 = b_hh[col],  bh1 = b_hh[256 + col],  bh2 = b_hh[512 + col];
    float wa0 = wamt[col],  wa1 = wamt[256 + col],  wa2 = wamt[512 + col];
    int hpart = colL >> 3, hbyte = (colL & 7) << 1;
    #pragma unroll
    for (int mf = 0; mf < 4; ++mf) {
        int rb = wr * 64 + mf * 16 + (lane >> 4) * 4;
        #pragma unroll
        for (int r = 0; r < 4; ++r) {
            int rl = rb + r;
            int grow = m0 + rl; if (grow >= M) grow = M - 1;
            int gid = ids[grow];
            float amtv = amt[grow];
            float hv = bf2f(*(const unsigned short*)(
                sh + rl * 128 + ((hpart ^ (rl & 7)) << 4) + hbyte));
            float ir = acc[0][mf][r] + bi0 + amtv * wa0;
            float iz = acc[1][mf][r] + bi1 + amtv * wa1;
            float in_ = acc[2][mf][r] + bi2 + amtv * wa2;
            float hr = acc[3][mf][r] + bh0;
            float hz = acc[4][mf][r] + bh1;
            float hn = acc[5][mf][r] + bh2;
            float rg = sigf(ir + hr);
            float zg = sigf(iz + hz);
            float ng = tanhfast(in_ + rg * hn);
            out_mem[(size_t)gid * 256 + col] = (1.f - zg) * ng + zg * hv;
        }
    }
}

// ---------------- copy: non-updated rows + lu merge, 4-row ILP ----------------
__global__ __launch_bounds__(256)
void copy_kernel(const float* __restrict__ memory,
                 const int* __restrict__ inv,
                 const float* __restrict__ lu,
                 const float* __restrict__ ts,
                 float* __restrict__ out_mem,
                 float* __restrict__ out_lu,
                 int N) {
    int wid = (blockIdx.x * blockDim.x + threadIdx.x) >> 6;
    int lane = threadIdx.x & 63;
    int nw = (gridDim.x * blockDim.x) >> 6;
    for (int base = wid; base < N; base += nw * 4) {
        int  r0 = base, r1 = base + nw, r2 = base + 2 * nw, r3 = base + 3 * nw;
        bool d0 = (r0 < N) && (inv[r0] == 0);
        bool d1 = (r1 < N) && (inv[r1] == 0);
        bool d2 = (r2 < N) && (inv[r2] == 0);
        bool d3 = (r3 < N) && (inv[r3] == 0);
        float4 v0, v1, v2, v3;
        if (d0) v0 = ((const float4*)(memory + (size_t)r0 * 256))[lane];
        if (d1) v1 = ((const float4*)(memory + (size_t)r1 * 256))[lane];
        if (d2) v2 = ((const float4*)(memory + (size_t)r2 * 256))[lane];
        if (d3) v3 = ((const float4*)(memory + (size_t)r3 * 256))[lane];
        if (d0) ((float4*)(out_mem + (size_t)r0 * 256))[lane] = v0;
        if (d1) ((float4*)(out_mem + (size_t)r1 * 256))[lane] = v1;
        if (d2) ((float4*)(out_mem + (size_t)r2 * 256))[lane] = v2;
        if (d3) ((float4*)(out_mem + (size_t)r3 * 256))[lane] = v3;
    }
    // last_update: single pass, no ordering hazard (inv/lu/ts L2-hot)
    int gidx = blockIdx.x * blockDim.x + threadIdx.x;
    int stride = gridDim.x * blockDim.x;
    for (int i = gidx; i < N; i += stride) {
        int iv = inv[i];
        out_lu[i] = iv ? ts[iv - 1] : lu[i];
    }
}

extern "C" void kernel_launch(void* const* d_in, const int* in_sizes, int n_in,
                              void* d_out, int out_size, void* d_ws, size_t ws_size,
                              hipStream_t stream) {
    const int*   ids   = (const int*)  d_in[0];
    const float* msgs  = (const float*)d_in[1];
    const float* ts    = (const float*)d_in[2];
    const float* amt   = (const float*)d_in[3];
    const float* mem   = (const float*)d_in[4];
    const float* lu    = (const float*)d_in[5];
    const float* W_cat = (const float*)d_in[6];
    const float* b_cat = (const float*)d_in[7];
    const float* W_ih  = (const float*)d_in[8];
    const float* W_hh  = (const float*)d_in[9];
    const float* b_ih  = (const float*)d_in[10];
    const float* b_hh  = (const float*)d_in[11];

    int M = in_sizes[0];
    int N = in_sizes[5];

    float* out_mem = (float*)d_out;
    float* out_lu  = out_mem + (size_t)N * 256;

    // ws layout: wm 384KB | whh 384KB | wamt 3KB | bcomb 3KB | inv 4N  (~2.8 MB)
    char* ws = (char*)d_ws;
    unsigned short* wm    = (unsigned short*)ws;
    unsigned short* whh   = wm + 768 * 256;
    float*          wamt  = (float*)(whh + 768 * 256);
    float*          bcomb = wamt + 768;
    int*            inv   = (int*)(bcomb + 768);

    (void)hipMemsetAsync(inv, 0, (size_t)N * 4, stream);

    int prep_items = 2 * 768 * 256 + 768 + M;
    prep_w_kernel<<<(prep_items + 255) / 256, 256, 0, stream>>>(
        W_cat, b_cat, W_ih, W_hh, b_ih, ids, wm, whh, wamt, bcomb, inv, M);

    int mtiles = (M + 127) / 128;
    int mt8 = ((mtiles + 7) / 8) * 8;
    (void)hipFuncSetAttribute((const void*)gru_kernel,
                              hipFuncAttributeMaxDynamicSharedMemorySize, 131072);
    gru_kernel<<<mt8 * 4, 512, 131072, stream>>>(
        ids, msgs, mem, wm, whh, wamt, bcomb, b_hh, amt, out_mem, M, mtiles);

    copy_kernel<<<2048, 256, 0, stream>>>(mem, inv, lu, ts, out_mem, out_lu, N);
}